// Round 1
// baseline (353.864 us; speedup 1.0000x reference)
//
#include <hip/hip_runtime.h>
#include <math.h>

// Problem constants (from reference): B=32, C=256, GROUPS=8 -> bg=256, cg=32, H=W=64
#define NPLANE 8192   // bg*cg
#define PLANE  4096   // 64*64

__device__ __forceinline__ float sigm(float v){ return 1.0f/(1.0f+expf(-v)); }

// ---------------- Kernel A: per-plane row sums, col sums, 4 corners ----------
// one block per (b,c) plane; 256 threads; each thread: 4 x float4
__global__ __launch_bounds__(256) void kA(const float* __restrict__ x,
                                          float* __restrict__ rowsum,
                                          float* __restrict__ colsum,
                                          float* __restrict__ corners){
  const int plane = blockIdx.x;
  const float* __restrict__ p = x + (size_t)plane*PLANE;
  const int t = threadIdx.x;
  __shared__ float cpart[256][4];
  __shared__ float rsh[64];
  float ca0=0.f, ca1=0.f, ca2=0.f, ca3=0.f;
  #pragma unroll
  for(int iter=0; iter<4; ++iter){
    const int flat = iter*1024 + t*4;
    const float4 v = *reinterpret_cast<const float4*>(p + flat);
    float rp = v.x+v.y+v.z+v.w;
    #pragma unroll
    for(int s=1;s<16;s<<=1) rp += __shfl_xor(rp, s, 64);
    if((t&15)==0) rsh[flat>>6] = rp;            // row = flat/64
    ca0+=v.x; ca1+=v.y; ca2+=v.z; ca3+=v.w;
    if(iter==0 && t==0)   corners[(size_t)plane*4+0]=v.x;  // (0,0)
    if(iter==0 && t==15)  corners[(size_t)plane*4+1]=v.w;  // (0,63)
    if(iter==3 && t==240) corners[(size_t)plane*4+2]=v.x;  // (63,0)
    if(iter==3 && t==255) corners[(size_t)plane*4+3]=v.w;  // (63,63)
  }
  cpart[t][0]=ca0; cpart[t][1]=ca1; cpart[t][2]=ca2; cpart[t][3]=ca3;
  __syncthreads();
  if(t<64){
    const int g=t>>2, j=t&3;   // col t: contributors have (tid&15)==g, element j
    float s=0.f;
    #pragma unroll
    for(int k=0;k<16;++k) s += cpart[g + k*16][j];
    colsum[(size_t)plane*64 + t] = s;
    rowsum[(size_t)plane*64 + t] = rsh[t];
  }
}

// ---------------- Kernel B0: x11 = softmax(gn_b) (data-independent),
//                  collapsed conv kernel wc[i][9], cb = x11·b3 ----------
__global__ __launch_bounds__(256) void kB0(const float* __restrict__ gn_b,
                                           const float* __restrict__ w3,
                                           const float* __restrict__ b3,
                                           float* __restrict__ wcg,
                                           float* __restrict__ cbg){
  __shared__ float x11[32];
  const int t=threadIdx.x;
  if(t==0){
    float m=-1e30f;
    #pragma unroll
    for(int c=0;c<32;++c) m=fmaxf(m,gn_b[c]);
    float e[32]; float s=0.f;
    #pragma unroll
    for(int c=0;c<32;++c){ e[c]=expf(gn_b[c]-m); s+=e[c]; }
    const float inv=1.f/s;
    float cb=0.f;
    #pragma unroll
    for(int c=0;c<32;++c){ x11[c]=e[c]*inv; cb+=x11[c]*b3[c]; }
    *cbg=cb;
  }
  __syncthreads();
  for(int idx=t; idx<288; idx+=256){
    const int i=idx/9, k=idx%9;
    float s=0.f;
    #pragma unroll
    for(int c=0;c<32;++c) s += x11[c]*w3[(c*32+i)*9+k];
    wcg[idx]=s;
  }
}

// ---------------- Kernel B: per-b (bg=256 blocks):
//   hw = w1 @ [rowmean;colmean] + b1 -> sigmoid -> sh, sw
//   mean(x2) per channel from marginals -> softmax -> x21 ----------
__global__ __launch_bounds__(256) void kB(const float* __restrict__ rowsum,
                                          const float* __restrict__ colsum,
                                          const float* __restrict__ corners,
                                          const float* __restrict__ w1,
                                          const float* __restrict__ b1,
                                          const float* __restrict__ w3,
                                          const float* __restrict__ b3,
                                          float* __restrict__ sh,
                                          float* __restrict__ sw,
                                          float* __restrict__ x21){
  const int b = blockIdx.x;
  const int t = threadIdx.x;
  __shared__ float m[32][128];   // [i][p]: p<64 rowmean, p>=64 colmean
  __shared__ float w1s[1024];
  __shared__ float S[32][9];
  __shared__ float mean2[32];
  const float* __restrict__ rs = rowsum + (size_t)b*32*64;
  const float* __restrict__ cs = colsum + (size_t)b*32*64;
  for(int idx=t; idx<2048; idx+=256){
    m[idx>>6][idx&63]        = rs[idx]*(1.0f/64.0f);
    m[idx>>6][64+(idx&63)]   = cs[idx]*(1.0f/64.0f);
  }
  for(int idx=t; idx<1024; idx+=256) w1s[idx]=w1[idx];
  __syncthreads();
  // hw matmul + sigmoid: thread t -> o=t>>3, positions p0..p0+15
  {
    const int o = t>>3;
    const int p0 = (t&7)<<4;
    const float bias = b1[o];
    #pragma unroll
    for(int pp=0;pp<16;++pp){
      const int p = p0+pp;
      float acc = bias;
      #pragma unroll
      for(int i=0;i<32;++i) acc += w1s[o*32+i]*m[i][p];
      const float sg = sigm(acc);
      if(p<64) sh[((size_t)b*32+o)*64 + p]      = sg;
      else     sw[((size_t)b*32+o)*64 + (p-64)] = sg;
    }
  }
  // region sums S[i][ky*3+kx] for conv-mean (ky=0 <-> oy=-1 excludes row 63, etc.)
  if(t<32){
    const int i=t;
    float Ti=0.f;
    #pragma unroll
    for(int h=0;h<64;++h) Ti += m[i][h];
    Ti *= 64.f;
    const float r0=m[i][0]*64.f, r63=m[i][63]*64.f;
    const float c0=m[i][64]*64.f, c63=m[i][127]*64.f;
    const float* cr = corners + ((size_t)b*32+i)*4;
    const float k00=cr[0], k01=cr[1], k10=cr[2], k11=cr[3]; // (0,0),(0,63),(63,0),(63,63)
    #pragma unroll
    for(int ky=0;ky<3;++ky){
      #pragma unroll
      for(int kx=0;kx<3;++kx){
        float s=Ti;
        if(ky==0) s-=r63; else if(ky==2) s-=r0;
        if(kx==0) s-=c63; else if(kx==2) s-=c0;
        if(ky==0&&kx==0) s+=k11;
        if(ky==0&&kx==2) s+=k10;
        if(ky==2&&kx==0) s+=k01;
        if(ky==2&&kx==2) s+=k00;
        S[i][ky*3+kx]=s;
      }
    }
  }
  __syncthreads();
  if(t<32){
    const int c=t;
    float acc=0.f;
    for(int i=0;i<32;++i){
      #pragma unroll
      for(int k=0;k<9;++k) acc += w3[(c*32+i)*9+k]*S[i][k];
    }
    mean2[c] = acc*(1.0f/4096.0f) + b3[c];
  }
  __syncthreads();
  if(t==0){
    float mx=-1e30f;
    #pragma unroll
    for(int c=0;c<32;++c) mx=fmaxf(mx,mean2[c]);
    float e[32]; float s=0.f;
    #pragma unroll
    for(int c=0;c<32;++c){ e[c]=expf(mean2[c]-mx); s+=e[c]; }
    const float inv=1.f/s;
    #pragma unroll
    for(int c=0;c<32;++c) x21[(size_t)b*32+c]=e[c]*inv;
  }
}

// ---------------- Kernel C: gated = gx*sh[h]*sw[w]; per-plane sum & sumsq ----
__global__ __launch_bounds__(256) void kC(const float* __restrict__ x,
                                          const float* __restrict__ sh,
                                          const float* __restrict__ sw,
                                          float* __restrict__ musum,
                                          float* __restrict__ sqsum){
  const int plane = blockIdx.x;
  const int t = threadIdx.x;
  const float* __restrict__ p = x + (size_t)plane*PLANE;
  __shared__ float shs[64], sws[64];
  if(t<64){ shs[t]=sh[(size_t)plane*64+t]; sws[t]=sw[(size_t)plane*64+t]; }
  __syncthreads();
  float s=0.f, q=0.f;
  #pragma unroll
  for(int iter=0;iter<4;++iter){
    const int flat=iter*1024 + t*4;
    const float4 v = *reinterpret_cast<const float4*>(p+flat);
    const int row=flat>>6, col=flat&63;
    const float a=shs[row];
    const float g0=v.x*a*sws[col+0], g1=v.y*a*sws[col+1];
    const float g2=v.z*a*sws[col+2], g3=v.w*a*sws[col+3];
    s += g0+g1+g2+g3;
    q += g0*g0+g1*g1+g2*g2+g3*g3;
  }
  #pragma unroll
  for(int sft=1;sft<64;sft<<=1){ s+=__shfl_xor(s,sft,64); q+=__shfl_xor(q,sft,64); }
  __shared__ float rsum[4], rsq[4];
  if((t&63)==0){ rsum[t>>6]=s; rsq[t>>6]=q; }
  __syncthreads();
  if(t==0){ musum[plane]=rsum[0]+rsum[1]+rsum[2]+rsum[3];
            sqsum[plane]=rsq[0]+rsq[1]+rsq[2]+rsq[3]; }
}

// ---------------- Kernel E: weights = wc*conv(gx) + sum_c alpha*sh*sw*gx + const
//                  out = gx*(1+sigmoid(weights)) -------------------------------
// grid: bg*4 blocks; block handles (b, 16-row tile), 256 threads -> 4 px/thread
__global__ __launch_bounds__(256) void kE(const float* __restrict__ x,
    const float* __restrict__ sh, const float* __restrict__ sw,
    const float* __restrict__ x21, const float* __restrict__ musum,
    const float* __restrict__ sqsum, const float* __restrict__ gn_w,
    const float* __restrict__ gn_b, const float* __restrict__ wc,
    const float* __restrict__ cb, float* __restrict__ out){
  const int b = blockIdx.x>>2;
  const int tile0 = (blockIdx.x&3)<<4;
  const int t = threadIdx.x;
  __shared__ float Lbuf[18][66];
  __shared__ float shs[32][16];
  __shared__ float sws[32][64];
  __shared__ float alphas[32];
  __shared__ float wcs[288];
  __shared__ float constsh;

  if(t<32){
    const float ms = musum[(size_t)b*32+t]*(1.0f/4096.0f);
    const float vv = sqsum[(size_t)b*32+t]*(1.0f/4096.0f) - ms*ms;
    const float rq = rsqrtf(vv + 1e-5f);
    const float xv = x21[(size_t)b*32+t];
    alphas[t] = xv*gn_w[t]*rq;
    float part = xv*(gn_b[t] - gn_w[t]*rq*ms);
    #pragma unroll
    for(int s=1;s<32;s<<=1) part += __shfl_xor(part, s, 64);
    if(t==0) constsh = part + cb[0];
  }
  for(int idx=t; idx<288; idx+=256) wcs[idx]=wc[idx];
  for(int idx=t; idx<512; idx+=256){
    const int i=idx>>4, r=idx&15;
    shs[i][r] = sh[((size_t)b*32+i)*64 + tile0 + r];
  }
  for(int idx=t; idx<2048; idx+=256){
    const int i=idx>>6, w=idx&63;
    sws[i][w] = sw[((size_t)b*32+i)*64 + w];
  }
  if(t<18){ Lbuf[t][0]=0.f; Lbuf[t][65]=0.f; }   // halo cols are always zero

  const int r  = t>>4;
  const int c0 = (t&15)<<2;
  float wacc0=0.f, wacc1=0.f, wacc2=0.f, wacc3=0.f;

  for(int i=0;i<32;++i){
    const float* __restrict__ p = x + ((size_t)b*32+i)*(size_t)PLANE;
    __syncthreads();                       // prev iteration's readers done
    for(int idx=t; idx<288; idx+=256){     // 18 rows x 16 float4
      const int rr=idx>>4, c4=(idx&15)<<2;
      const int gr=tile0+rr-1;
      float4 v = make_float4(0.f,0.f,0.f,0.f);
      if(gr>=0 && gr<64) v = *reinterpret_cast<const float4*>(p + gr*64 + c4);
      Lbuf[rr][c4+1]=v.x; Lbuf[rr][c4+2]=v.y; Lbuf[rr][c4+3]=v.z; Lbuf[rr][c4+4]=v.w;
    }
    __syncthreads();
    const float q0=wcs[i*9+0], q1=wcs[i*9+1], q2=wcs[i*9+2];
    const float q3=wcs[i*9+3], q4=wcs[i*9+4], q5=wcs[i*9+5];
    const float q6=wcs[i*9+6], q7=wcs[i*9+7], q8=wcs[i*9+8];
    const float ash = alphas[i]*shs[i][r];
    #pragma unroll
    for(int j=0;j<4;++j){
      const int cc=c0+j+1;
      const float a0=Lbuf[r  ][cc-1], a1=Lbuf[r  ][cc], a2=Lbuf[r  ][cc+1];
      const float e0=Lbuf[r+1][cc-1], e1=Lbuf[r+1][cc], e2=Lbuf[r+1][cc+1];
      const float d0=Lbuf[r+2][cc-1], d1=Lbuf[r+2][cc], d2=Lbuf[r+2][cc+1];
      float acc = q0*a0+q1*a1+q2*a2 + q3*e0+q4*e1+q5*e2 + q6*d0+q7*d1+q8*d2;
      acc += ash*sws[i][c0+j]*e1;          // alpha*sh*sw*gx (center)
      if(j==0) wacc0+=acc; else if(j==1) wacc1+=acc;
      else if(j==2) wacc2+=acc; else wacc3+=acc;
    }
  }
  __syncthreads();
  const float cst = constsh;
  const float wf0 = 1.f + sigm(wacc0+cst);
  const float wf1 = 1.f + sigm(wacc1+cst);
  const float wf2 = 1.f + sigm(wacc2+cst);
  const float wf3 = 1.f + sigm(wacc3+cst);
  const size_t rowoff = (size_t)(tile0+r)*64 + c0;
  for(int i=0;i<32;++i){
    const size_t off = ((size_t)b*32+i)*(size_t)PLANE + rowoff;
    const float4 v = *reinterpret_cast<const float4*>(x + off);
    float4 o;
    o.x=v.x*wf0; o.y=v.y*wf1; o.z=v.z*wf2; o.w=v.w*wf3;
    *reinterpret_cast<float4*>(out + off) = o;
  }
}

extern "C" void kernel_launch(void* const* d_in, const int* in_sizes, int n_in,
                              void* d_out, int out_size, void* d_ws, size_t ws_size,
                              hipStream_t stream){
  (void)in_sizes; (void)n_in; (void)out_size; (void)ws_size;
  const float* x    = (const float*)d_in[0];
  const float* w1   = (const float*)d_in[1];
  const float* b1   = (const float*)d_in[2];
  const float* w3   = (const float*)d_in[3];
  const float* b3   = (const float*)d_in[4];
  const float* gn_w = (const float*)d_in[5];
  const float* gn_b = (const float*)d_in[6];
  float* out = (float*)d_out;
  float* ws  = (float*)d_ws;

  // workspace layout (floats); total ~2.15M floats = 8.6 MB
  float* rowsum  = ws + 0;        // 8192*64
  float* colsum  = ws + 524288;   // 8192*64
  float* corners = ws + 1048576;  // 8192*4
  float* sh      = ws + 1081344;  // 8192*64
  float* sw      = ws + 1605632;  // 8192*64
  float* x21     = ws + 2129920;  // 8192
  float* musum   = ws + 2138112;  // 8192
  float* sqsum   = ws + 2146304;  // 8192
  float* wc      = ws + 2154496;  // 288
  float* cb      = ws + 2154784;  // 1

  kA <<<NPLANE, 256, 0, stream>>>(x, rowsum, colsum, corners);
  kB0<<<1,      256, 0, stream>>>(gn_b, w3, b3, wc, cb);
  kB <<<256,    256, 0, stream>>>(rowsum, colsum, corners, w1, b1, w3, b3, sh, sw, x21);
  kC <<<NPLANE, 256, 0, stream>>>(x, sh, sw, musum, sqsum);
  kE <<<1024,   256, 0, stream>>>(x, sh, sw, x21, musum, sqsum, gn_w, gn_b, wc, cb, out);
}

// Round 5
// 343.621 us; speedup vs baseline: 1.0298x; 1.0298x over previous
//
#include <hip/hip_runtime.h>
#include <math.h>

// Problem constants: B=32, C=256, GROUPS=8 -> bg=256, cg=32, H=W=64
#define NPLANE 8192   // bg*cg
#define PLANE  4096   // 64*64

__device__ __forceinline__ float sigm(float v){ return 1.0f/(1.0f+expf(-v)); }

// ---------------- Kernel A: per-plane row sums, col sums, 4 corners ----------
__global__ __launch_bounds__(256) void kA(const float* __restrict__ x,
                                          float* __restrict__ rowsum,
                                          float* __restrict__ colsum,
                                          float* __restrict__ corners){
  const int plane = blockIdx.x;
  const float* __restrict__ p = x + (size_t)plane*PLANE;
  const int t = threadIdx.x;
  __shared__ float cpart[256][5];
  __shared__ float rsh[64];
  float4 v[4];
  #pragma unroll
  for(int it=0; it<4; ++it)
    v[it] = *reinterpret_cast<const float4*>(p + it*1024 + t*4);
  // corners (0,0),(0,63),(63,0),(63,63)
  if(t==0)   corners[(size_t)plane*4+0]=v[0].x;
  if(t==15)  corners[(size_t)plane*4+1]=v[0].w;
  if(t==240) corners[(size_t)plane*4+2]=v[3].x;
  if(t==255) corners[(size_t)plane*4+3]=v[3].w;
  float ca0=0.f, ca1=0.f, ca2=0.f, ca3=0.f;
  #pragma unroll
  for(int it=0; it<4; ++it){
    float rp = v[it].x+v[it].y+v[it].z+v[it].w;
    #pragma unroll
    for(int s=1;s<16;s<<=1) rp += __shfl_xor(rp, s, 64);
    if((t&15)==0) rsh[it*16 + (t>>4)] = rp;
    ca0+=v[it].x; ca1+=v[it].y; ca2+=v[it].z; ca3+=v[it].w;
  }
  cpart[t][0]=ca0; cpart[t][1]=ca1; cpart[t][2]=ca2; cpart[t][3]=ca3;
  __syncthreads();
  if(t<64){
    const int g=t>>2, j=t&3;
    float s=0.f;
    #pragma unroll
    for(int k=0;k<16;++k) s += cpart[g + k*16][j];
    colsum[(size_t)plane*64 + t] = s;
    rowsum[(size_t)plane*64 + t] = rsh[t];
  }
}

// ---------------- Kernel B0: x11 = softmax(gn_b); wc[i][9]; cb ----------
__global__ __launch_bounds__(256) void kB0(const float* __restrict__ gn_b,
                                           const float* __restrict__ w3,
                                           const float* __restrict__ b3,
                                           float* __restrict__ wcg,
                                           float* __restrict__ cbg){
  __shared__ float x11[32];
  const int t=threadIdx.x;
  if(t==0){
    float m=-1e30f;
    #pragma unroll
    for(int c=0;c<32;++c) m=fmaxf(m,gn_b[c]);
    float e[32]; float s=0.f;
    #pragma unroll
    for(int c=0;c<32;++c){ e[c]=expf(gn_b[c]-m); s+=e[c]; }
    const float inv=1.f/s;
    float cb=0.f;
    #pragma unroll
    for(int c=0;c<32;++c){ x11[c]=e[c]*inv; cb+=x11[c]*b3[c]; }
    *cbg=cb;
  }
  __syncthreads();
  for(int idx=t; idx<288; idx+=256){
    const int i=idx/9, k=idx%9;
    float s=0.f;
    #pragma unroll
    for(int c=0;c<32;++c) s += x11[c]*w3[(c*32+i)*9+k];
    wcg[idx]=s;
  }
}

// ---------------- Kernel B: sh/sw gates + x21 softmax, per b ----------
__global__ __launch_bounds__(256) void kB(const float* __restrict__ rowsum,
                                          const float* __restrict__ colsum,
                                          const float* __restrict__ corners,
                                          const float* __restrict__ w1,
                                          const float* __restrict__ b1,
                                          const float* __restrict__ w3,
                                          const float* __restrict__ b3,
                                          float* __restrict__ sh,
                                          float* __restrict__ sw,
                                          float* __restrict__ x21){
  const int b = blockIdx.x;
  const int t = threadIdx.x;
  __shared__ float m[32*132];     // padded stride 132
  __shared__ float w1t[1024];     // [i*32+o]
  __shared__ float w3t[9216];     // [(i*9+k)*32+c]
  __shared__ float sout[32*132];  // padded stride 132: [o][p]
  __shared__ float S[288];
  __shared__ float red[256];
  const float* __restrict__ rs = rowsum + (size_t)b*2048;
  const float* __restrict__ cs = colsum + (size_t)b*2048;
  for(int idx=t; idx<2048; idx+=256){
    const int i=idx>>6, h=idx&63;
    m[i*132+h]    = rs[idx]*(1.0f/64.0f);
    m[i*132+64+h] = cs[idx]*(1.0f/64.0f);
  }
  for(int idx=t; idx<1024; idx+=256) w1t[idx] = w1[(idx&31)*32 + (idx>>5)];
  for(int idx=t; idx<9216; idx+=256){
    const int c=idx&31, r=idx>>5, i=r/9, k=r-9*i;
    w3t[idx] = w3[(c*32+i)*9+k];
  }
  __syncthreads();
  // hw matmul + sigmoid: o = t&31 (lanes spread o -> conflict-free weights,
  // broadcast m), p-group = t>>5
  {
    const int o = t&31, pg = t>>5;
    const float bo = b1[o];
    #pragma unroll
    for(int pp=0;pp<16;++pp){
      const int p = pg*16+pp;
      float a = bo;
      #pragma unroll
      for(int i=0;i<32;++i) a += w1t[i*32+o]*m[i*132+p];
      sout[o*132+p] = sigm(a);
    }
  }
  // region sums for conv-mean
  if(t<32){
    const int i=t;
    float Ti=0.f;
    for(int h=0;h<64;++h) Ti += m[i*132+h];
    Ti *= 64.f;
    const float r0=m[i*132+0]*64.f, r63=m[i*132+63]*64.f;
    const float c0=m[i*132+64]*64.f, c63=m[i*132+127]*64.f;
    const float* cr = corners + ((size_t)b*32+i)*4;
    const float k00=cr[0], k01=cr[1], k10=cr[2], k11=cr[3];
    #pragma unroll
    for(int ky=0;ky<3;++ky){
      #pragma unroll
      for(int kx=0;kx<3;++kx){
        float s=Ti;
        if(ky==0) s-=r63; else if(ky==2) s-=r0;
        if(kx==0) s-=c63; else if(kx==2) s-=c0;
        if(ky==0&&kx==0) s+=k11;
        if(ky==0&&kx==2) s+=k10;
        if(ky==2&&kx==0) s+=k01;
        if(ky==2&&kx==2) s+=k00;
        S[i*9+ky*3+kx]=s;
      }
    }
  }
  __syncthreads();
  // mean(x2) matvec, 8-way split over i
  {
    const int c = t&31, chunk = t>>5;
    float part = 0.f;
    #pragma unroll
    for(int ii=0; ii<4; ++ii){
      const int i = chunk*4+ii;
      #pragma unroll
      for(int k=0;k<9;++k) part += w3t[(i*9+k)*32+c]*S[i*9+k];
    }
    red[t] = part;
  }
  __syncthreads();
  if(t<32){
    float mm=0.f;
    #pragma unroll
    for(int ch=0;ch<8;++ch) mm += red[ch*32+t];
    mm = mm*(1.0f/4096.0f) + b3[t];
    float mx = mm;
    #pragma unroll
    for(int s=1;s<32;s<<=1) mx = fmaxf(mx, __shfl_xor(mx,s,64));
    const float e = expf(mm-mx);
    float ss = e;
    #pragma unroll
    for(int s=1;s<32;s<<=1) ss += __shfl_xor(ss,s,64);
    x21[(size_t)b*32+t] = e/ss;
  }
  // coalesced sh/sw write-out
  for(int idx=t; idx<2048; idx+=256){
    sh[(size_t)b*2048+idx] = sout[(idx>>6)*132 + (idx&63)];
    sw[(size_t)b*2048+idx] = sout[(idx>>6)*132 + 64 + (idx&63)];
  }
}

// ---------------- Kernel C: gated stats (sum, sumsq) per plane ----------
__global__ __launch_bounds__(256) void kC(const float* __restrict__ x,
                                          const float* __restrict__ sh,
                                          const float* __restrict__ sw,
                                          float* __restrict__ musum,
                                          float* __restrict__ sqsum){
  const int plane = blockIdx.x;
  const int t = threadIdx.x;
  const float* __restrict__ p = x + (size_t)plane*PLANE;
  __shared__ float shs[64], sws[64];
  float4 v[4];
  #pragma unroll
  for(int it=0;it<4;++it)
    v[it] = *reinterpret_cast<const float4*>(p + it*1024 + t*4);
  if(t<64){ shs[t]=sh[(size_t)plane*64+t]; sws[t]=sw[(size_t)plane*64+t]; }
  __syncthreads();
  const int col = (t&15)<<2;
  const float4 swv = *reinterpret_cast<const float4*>(&sws[col]);
  float s=0.f, q=0.f;
  #pragma unroll
  for(int it=0;it<4;++it){
    const float a = shs[it*16 + (t>>4)];
    const float g0=v[it].x*a*swv.x, g1=v[it].y*a*swv.y;
    const float g2=v[it].z*a*swv.z, g3=v[it].w*a*swv.w;
    s += g0+g1+g2+g3;
    q += g0*g0+g1*g1+g2*g2+g3*g3;
  }
  #pragma unroll
  for(int sft=1;sft<64;sft<<=1){ s+=__shfl_xor(s,sft,64); q+=__shfl_xor(q,sft,64); }
  __shared__ float rsum[4], rsq[4];
  if((t&63)==0){ rsum[t>>6]=s; rsq[t>>6]=q; }
  __syncthreads();
  if(t==0){ musum[plane]=rsum[0]+rsum[1]+rsum[2]+rsum[3];
            sqsum[plane]=rsq[0]+rsq[1]+rsq[2]+rsq[3]; }
}

// ---------------- Kernel E: register tap-accumulate conv + gated + output ----
// grid = bg*4; block 320 threads; threads 0..287 own one float4 of the
// 18-row halo tile (halo row hr = t>>4, cols (t&15)*4 ..+3).
// Channel loop: no barriers, 1 coalesced load + 9 tap FMAs + gated FMA /px.
#define TEB 320
__global__ __launch_bounds__(TEB) void kE(const float* __restrict__ x,
    const float* __restrict__ sh, const float* __restrict__ sw,
    const float* __restrict__ x21, const float* __restrict__ musum,
    const float* __restrict__ sqsum, const float* __restrict__ gn_w,
    const float* __restrict__ gn_b, const float* __restrict__ wc,
    const float* __restrict__ cb, float* __restrict__ out){
  const int b = blockIdx.x>>2;
  const int tile0 = (blockIdx.x&3)<<4;
  const int t = threadIdx.x;
  __shared__ float H[3*18*68];    // horizontal-combined tap maps per ky
  __shared__ float sws[32*64];
  __shared__ float shs[32*16];
  __shared__ float alphas[32];
  __shared__ float wcs[292];
  __shared__ float constsh;

  if(t<32){
    const float ms = musum[(size_t)b*32+t]*(1.0f/4096.0f);
    const float vv = sqsum[(size_t)b*32+t]*(1.0f/4096.0f) - ms*ms;
    const float rq = rsqrtf(vv + 1e-5f);
    const float xv = x21[(size_t)b*32+t];
    alphas[t] = xv*gn_w[t]*rq;
    float part = xv*(gn_b[t] - gn_w[t]*rq*ms);
    #pragma unroll
    for(int s=1;s<32;s<<=1) part += __shfl_xor(part, s, 64);
    if(t==0) constsh = part + cb[0];
  }
  for(int idx=t; idx<288; idx+=TEB) wcs[idx]=wc[idx];
  for(int idx=t; idx<512; idx+=TEB)
    shs[idx] = sh[(size_t)b*2048 + (idx>>4)*64 + tile0 + (idx&15)];
  for(int idx=t; idx<2048; idx+=TEB)
    sws[idx] = sw[(size_t)b*2048 + idx];
  __syncthreads();

  const int hr = t>>4;            // halo row 0..17 (global row tile0+hr-1)
  const int c0 = (t&15)<<2;
  const int gr = tile0 + hr - 1;
  float acc[4][9];
  float gacc[4];

  if(t < 288){
    #pragma unroll
    for(int j=0;j<4;++j){
      gacc[j]=0.f;
      #pragma unroll
      for(int k=0;k<9;++k) acc[j][k]=0.f;
    }
    const float rowmask = (hr>=1 && hr<=16) ? 1.f : 0.f;
    const int   shi = min(max(hr-1,0),15);
    const bool  inrow = (gr>=0) && (gr<64);
    const float* __restrict__ px = x + ((size_t)b*32)*PLANE + (size_t)gr*64 + c0;
    #pragma unroll 2
    for(int i=0;i<32;++i){
      float4 v = make_float4(0.f,0.f,0.f,0.f);
      if(inrow) v = *reinterpret_cast<const float4*>(px + (size_t)i*PLANE);
      const float ash = alphas[i]*shs[i*16+shi]*rowmask;
      const float4 swv = *reinterpret_cast<const float4*>(&sws[i*64+c0]);
      const float* __restrict__ wq = &wcs[i*9];
      const float vv0=v.x, vv1=v.y, vv2=v.z, vv3=v.w;
      #pragma unroll
      for(int k=0;k<9;++k){
        const float w = wq[k];
        acc[0][k] += w*vv0; acc[1][k] += w*vv1;
        acc[2][k] += w*vv2; acc[3][k] += w*vv3;
      }
      gacc[0] += ash*swv.x*vv0; gacc[1] += ash*swv.y*vv1;
      gacc[2] += ash*swv.z*vv2; gacc[3] += ash*swv.w*vv3;
    }
    // horizontal 3-tap combine: H_ky[c] = t_{ky,0}[c-1]+t_{ky,1}[c]+t_{ky,2}[c+1]
    #pragma unroll
    for(int ky=0;ky<3;++ky){
      float lf = __shfl_up(acc[3][ky*3+0], 1);
      float rt = __shfl_down(acc[0][ky*3+2], 1);
      if(c0==0)  lf = 0.f;
      if(c0==60) rt = 0.f;
      const float h0 = lf             + acc[0][ky*3+1] + acc[1][ky*3+2];
      const float h1 = acc[0][ky*3+0] + acc[1][ky*3+1] + acc[2][ky*3+2];
      const float h2 = acc[1][ky*3+0] + acc[2][ky*3+1] + acc[3][ky*3+2];
      const float h3 = acc[2][ky*3+0] + acc[3][ky*3+1] + rt;
      *reinterpret_cast<float4*>(&H[(ky*18+hr)*68 + c0]) = make_float4(h0,h1,h2,h3);
    }
  }
  __syncthreads();
  if(t>=16 && t<272){
    const float4 h0 = *reinterpret_cast<const float4*>(&H[(0*18 + hr-1)*68 + c0]);
    const float4 h1 = *reinterpret_cast<const float4*>(&H[(1*18 + hr  )*68 + c0]);
    const float4 h2 = *reinterpret_cast<const float4*>(&H[(2*18 + hr+1)*68 + c0]);
    const float cst = constsh;
    const float wf0 = 1.f + sigm(h0.x+h1.x+h2.x + gacc[0] + cst);
    const float wf1 = 1.f + sigm(h0.y+h1.y+h2.y + gacc[1] + cst);
    const float wf2 = 1.f + sigm(h0.z+h1.z+h2.z + gacc[2] + cst);
    const float wf3 = 1.f + sigm(h0.w+h1.w+h2.w + gacc[3] + cst);
    const float* __restrict__ px = x   + ((size_t)b*32)*PLANE + (size_t)gr*64 + c0;
    float*       __restrict__ po = out + ((size_t)b*32)*PLANE + (size_t)gr*64 + c0;
    #pragma unroll 4
    for(int i=0;i<32;++i){
      const float4 v = *reinterpret_cast<const float4*>(px + (size_t)i*PLANE);
      float4 o;
      o.x=v.x*wf0; o.y=v.y*wf1; o.z=v.z*wf2; o.w=v.w*wf3;
      *reinterpret_cast<float4*>(po + (size_t)i*PLANE) = o;
    }
  }
}

extern "C" void kernel_launch(void* const* d_in, const int* in_sizes, int n_in,
                              void* d_out, int out_size, void* d_ws, size_t ws_size,
                              hipStream_t stream){
  (void)in_sizes; (void)n_in; (void)out_size; (void)ws_size;
  const float* x    = (const float*)d_in[0];
  const float* w1   = (const float*)d_in[1];
  const float* b1   = (const float*)d_in[2];
  const float* w3   = (const float*)d_in[3];
  const float* b3   = (const float*)d_in[4];
  const float* gn_w = (const float*)d_in[5];
  const float* gn_b = (const float*)d_in[6];
  float* out = (float*)d_out;
  float* ws  = (float*)d_ws;

  float* rowsum  = ws + 0;        // 8192*64
  float* colsum  = ws + 524288;   // 8192*64
  float* corners = ws + 1048576;  // 8192*4
  float* sh      = ws + 1081344;  // 8192*64
  float* sw      = ws + 1605632;  // 8192*64
  float* x21     = ws + 2129920;  // 8192
  float* musum   = ws + 2138112;  // 8192
  float* sqsum   = ws + 2146304;  // 8192
  float* wc      = ws + 2154496;  // 288
  float* cb      = ws + 2154784;  // 1

  kA <<<NPLANE, 256, 0, stream>>>(x, rowsum, colsum, corners);
  kB0<<<1,      256, 0, stream>>>(gn_b, w3, b3, wc, cb);
  kB <<<256,    256, 0, stream>>>(rowsum, colsum, corners, w1, b1, w3, b3, sh, sw, x21);
  kC <<<NPLANE, 256, 0, stream>>>(x, sh, sw, musum, sqsum);
  kE <<<1024,   TEB, 0, stream>>>(x, sh, sw, x21, musum, sqsum, gn_w, gn_b, wc, cb, out);
}